// Round 8
// baseline (132.730 us; speedup 1.0000x reference)
//
#include <hip/hip_runtime.h>
#include <stdint.h>

typedef unsigned uint;
typedef unsigned long long ull;

#define DIMS   4096
#define NT     256
#define WPB    4             // independent waves (rows) per block, ZERO barriers
#define KSEL   16            // top-k per branch (KTOP/2)
#define CMAX   64            // candidate capacity per branch
#define ALPHA_C 6.26f
#define PIV0   0x40133333u   // bits(2.3f): ~44 expected survivors per branch
#define PIVN   0xC0133333u   // raw >= PIVN (unsigned)  <=>  neg-key >= PIV0

#define BPk(raw) (((int)(raw) > 0) ? (raw) : 0u)                  // key of relu(x)
#define BNk(raw) (((int)(raw) < 0) ? ((raw) ^ 0x80000000u) : 0u)  // key of max(-x,0)
// element index of chunk J, comp C in this lane: idx = J*256 + lane*4 + C
// inverted so smaller index -> larger low word (jax tie-break: lowest index first)
#define INV(J,C) (~((((uint)(J)) << 8) + (((uint)lane) << 2) + ((uint)(C))))

__device__ __forceinline__ float wave_fadd(float v) {
#pragma unroll
  for (int off = 1; off < 64; off <<= 1) v += __shfl_xor(v, off, 64);
  return v;
}
__device__ __forceinline__ uint wave_uadd(uint v) {
#pragma unroll
  for (int off = 1; off < 64; off <<= 1) v += __shfl_xor(v, off, 64);
  return v;
}
__device__ __forceinline__ ull shflx64(ull v, int m) {
  uint lo = (uint)v, hi = (uint)(v >> 32);
  lo = __shfl_xor(lo, m, 64);
  hi = __shfl_xor(hi, m, 64);
  return (((ull)hi) << 32) | lo;
}
__device__ __forceinline__ ull shflb64(ull v, int src) {
  uint lo = (uint)v, hi = (uint)(v >> 32);
  lo = __shfl(lo, src, 64);
  hi = __shfl(hi, src, 64);
  return (((ull)hi) << 32) | lo;
}

// (NT,6) -> ~85 VGPR budget: transient streaming needs ~56; no spill headroom
// issues (R6 lesson: (NT,8)=64-cap spilled; R2/R3 lesson: never hold the row).
__global__ __launch_bounds__(NT, 6) void kcomp_kernel(const float* __restrict__ x,
                                                      float* __restrict__ out) {
  const int tid  = threadIdx.x;
  const int lane = tid & 63;
  const int wid  = tid >> 6;
  const int row  = blockIdx.x * WPB + wid;

  __shared__ ull  s_cand[WPB][2][CMAX];   // 4 KB, per-wave segments
  __shared__ uint s_cnt[WPB][2];          // per-wave counters

  ull* buf0 = s_cand[wid][0];
  ull* buf1 = s_cand[wid][1];
  if (lane == 0) { s_cnt[wid][0] = 0u; s_cnt[wid][1] = 0u; }  // same-wave DS: in-order

  const uint4* xr4 = reinterpret_cast<const uint4*>(x + (size_t)row * DIMS);

  // ---- pass 1: stream row; fused sums + speculative gather at the statistical pivot ----
  float psum = 0.f, nmsum = 0.f;   // nmsum = sum of min(x,0)
#pragma unroll
  for (int j = 0; j < 16; ++j) {
    uint4 v = xr4[j * 64 + lane];
#define PROC(RW, C) { \
    float f = __uint_as_float(RW); \
    psum += fmaxf(f, 0.f); nmsum += fminf(f, 0.f); \
    if ((int)(RW) >= (int)PIV0) { \
      ull K = (((ull)(RW)) << 32) | (ull)INV(j, C); \
      uint s = atomicAdd(&s_cnt[wid][0], 1u); if (s < CMAX) buf0[s] = K; } \
    if ((RW) >= PIVN) { \
      ull K = (((ull)((RW) ^ 0x80000000u)) << 32) | (ull)INV(j, C); \
      uint s = atomicAdd(&s_cnt[wid][1], 1u); if (s < CMAX) buf1[s] = K; } }
    PROC(v.x, 0) PROC(v.y, 1) PROC(v.z, 2) PROC(v.w, 3)
#undef PROC
  }

  psum = wave_fadd(psum);
  float nsum = -wave_fadd(nmsum);

  uint ns0 = s_cnt[wid][0];   // same-wave DS ordering: atomics visible, no barrier
  uint ns1 = s_cnt[wid][1];
  const bool bad0 = (ns0 < KSEL) | (ns0 > CMAX);
  const bool bad1 = (ns1 < KSEL) | (ns1 > CMAX);

  // ---- cold path (~0.3% of rows, wave-uniform): bisect over global (L2-hot) + regather ----
  if (bad0 | bad1) {
    for (int br = 0; br < 2; ++br) {
      const bool bad = br ? bad1 : bad0;
      if (!bad) continue;
      const uint ns = br ? ns1 : ns0;
      uint lo, hi, nlo;
      if (ns > CMAX) { lo = PIV0; hi = 0xFFFFFFFFu; nlo = ns; }
      else           { lo = 0u;   hi = PIV0;        nlo = (uint)DIMS; }
      bool st2 = false;
      for (int it = 0; it < 40; ++it) {
        if (hi - lo <= 1u) { st2 = (nlo > CMAX); break; }
        const uint mid = lo + ((hi - lo) >> 1);
        uint c = 0;
        for (int j = 0; j < 16; ++j) {
          uint4 v = xr4[j * 64 + lane];
#define CNT(RW) { uint k = br ? BNk(RW) : BPk(RW); c += (k >= mid) ? 1u : 0u; }
          CNT(v.x) CNT(v.y) CNT(v.z) CNT(v.w)
#undef CNT
        }
        const uint t = wave_uadd(c);
        if (t >= KSEL) { lo = mid; nlo = t; if (t <= CMAX) break; }
        else hi = mid;
      }
      ull S;
      if (!st2) S = ((ull)lo) << 32;
      else {
        // >CMAX exact bit-ties at pivot: bisect the inverted-index word
        const uint pivot = lo;
        uint lo2 = 0u, hi2 = 0xFFFFFFFFu, nlo2 = nlo;
        for (int it = 0; it < 34 && nlo2 > CMAX; ++it) {
          const uint mid2 = lo2 + ((hi2 - lo2) >> 1);
          uint c = 0;
          for (int j = 0; j < 16; ++j) {
            uint4 v = xr4[j * 64 + lane];
#define CNT2(RW, C) { uint k = br ? BNk(RW) : BPk(RW); \
            c += ((k > pivot) || (k == pivot && INV(j, C) >= mid2)) ? 1u : 0u; }
            CNT2(v.x, 0) CNT2(v.y, 1) CNT2(v.z, 2) CNT2(v.w, 3)
#undef CNT2
          }
          const uint n = wave_uadd(c);
          if (n >= KSEL) { lo2 = mid2; nlo2 = n; } else hi2 = mid2;
          if (hi2 - lo2 <= 1u) break;  // unique 64-bit keys => count <= CMAX
        }
        S = (((ull)pivot) << 32) | (ull)lo2;
      }
      // regather this branch (own counter: wave-local reset is in-order)
      if (lane == 0) s_cnt[wid][br] = 0u;
      ull* buf = br ? buf1 : buf0;
      for (int j = 0; j < 16; ++j) {
        uint4 v = xr4[j * 64 + lane];
#define RGAT(RW, C) { uint k = br ? BNk(RW) : BPk(RW); \
        ull K = (((ull)k) << 32) | (ull)INV(j, C); \
        if (K >= S) { uint s = atomicAdd(&s_cnt[wid][br], 1u); if (s < CMAX) buf[s] = K; } }
        RGAT(v.x, 0) RGAT(v.y, 1) RGAT(v.z, 2) RGAT(v.w, 3)
#undef RGAT
      }
    }
    ns0 = s_cnt[wid][0];
    ns1 = s_cnt[wid][1];
  }

  // ---- exact top-16 per branch: dual bitonic sort in this wave (ILP-paired) ----
  const uint n0 = (ns0 > CMAX) ? CMAX : ns0;
  const uint n1 = (ns1 > CMAX) ? CMAX : ns1;
  ull v0 = ((uint)lane < n0) ? buf0[lane] : 0ull;   // real keys are nonzero
  ull v1 = ((uint)lane < n1) ? buf1[lane] : 0ull;

#pragma unroll
  for (int k = 2; k <= 64; k <<= 1) {
#pragma unroll
    for (int j = k >> 1; j > 0; j >>= 1) {
      const ull o0 = shflx64(v0, j);
      const ull o1 = shflx64(v1, j);
      const bool keepmin = (((lane & k) == 0) == ((lane & j) == 0));
      const ull mn0 = (v0 < o0) ? v0 : o0, mx0 = (v0 < o0) ? o0 : v0;
      const ull mn1 = (v1 < o1) ? v1 : o1, mx1 = (v1 < o1) ? o1 : v1;
      v0 = keepmin ? mn0 : mx0;
      v1 = keepmin ? mn1 : mx1;
    }
  }
  // ascending: lanes 48..63 hold the top-16; lane 48 = 16th-largest (threshold)
  float tv0 = __uint_as_float((uint)(v0 >> 32));
  float tv1 = __uint_as_float((uint)(v1 >> 32));
#pragma unroll
  for (int off = 1; off < 16; off <<= 1) {  // 16-lane-group sums; valid within [48,63]
    tv0 += __shfl_xor(tv0, off, 64);
    tv1 += __shfl_xor(tv1, off, 64);
  }
  const ull T0 = shflb64(v0, 48);
  const ull T1 = shflb64(v1, 48);
  const float a0 = ALPHA_C * (psum - __shfl(tv0, 48, 64));
  const float a1 = ALPHA_C * (nsum - __shfl(tv1, 48, 64));

  // ---- pass 2: re-stream row from L2/L3 and emit densely (ideal write traffic) ----
  float4* o4 = reinterpret_cast<float4*>(out + (size_t)row * DIMS);
#pragma unroll
  for (int j = 0; j < 16; ++j) {
    uint4 v = xr4[j * 64 + lane];
    float4 o;
#define EMIT(RW, C, DST) { \
    uint bp = BPk(RW), bn = BNk(RW); \
    ull Kp = (((ull)bp) << 32) | (ull)INV(j, C); \
    ull Kn = (((ull)bn) << 32) | (ull)INV(j, C); \
    float r = 0.f; \
    if (Kp >= T0) r  = __uint_as_float(bp) + a0; \
    if (Kn >= T1) r -= __uint_as_float(bn) + a1; \
    DST = r; }
    EMIT(v.x, 0, o.x) EMIT(v.y, 1, o.y) EMIT(v.z, 2, o.z) EMIT(v.w, 3, o.w)
#undef EMIT
    o4[j * 64 + lane] = o;
  }
}

extern "C" void kernel_launch(void* const* d_in, const int* in_sizes, int n_in,
                              void* d_out, int out_size, void* d_ws, size_t ws_size,
                              hipStream_t stream) {
  const float* x = (const float*)d_in[0];
  float* o = (float*)d_out;
  const int B = in_sizes[0] / DIMS;   // 8192 rows
  hipLaunchKernelGGL(kcomp_kernel, dim3(B / WPB), dim3(NT), 0, stream, x, o);
}

// Round 9
// 52.186 us; speedup vs baseline: 2.5434x; 2.5434x over previous
//
#include <hip/hip_runtime.h>
#include <stdint.h>

typedef unsigned uint;
typedef unsigned long long ull;

#define DIMS   4096
#define NT     256
#define KSEL   16            // top-k per branch (KTOP/2)
#define CMAX   64            // candidate capacity per branch
#define ALPHA_C 6.26f
#define PIV0   0x40133333u   // bits(2.3f): ~44 expected survivors per branch
#define PIVN   0xC0133333u   // raw >= PIVN (unsigned)  <=>  neg-key >= PIV0

#define BPk(raw) (((int)(raw) > 0) ? (raw) : 0u)                  // key of relu(x)
#define BNk(raw) (((int)(raw) < 0) ? ((raw) ^ 0x80000000u) : 0u)  // key of max(-x,0)
// element index of chunk J, comp C in this thread: idx = J*1024 + tid*4 + C
// inverted so smaller index -> larger low word (jax tie-break: lowest index first)
#define INV(J,C) (~((((uint)(J)) << 10) + (((uint)tid) << 2) + ((uint)(C))))

__device__ __forceinline__ ull shflx64(ull v, int m) {
  uint lo = (uint)v, hi = (uint)(v >> 32);
  lo = __shfl_xor(lo, m, 64);
  hi = __shfl_xor(hi, m, 64);
  return (((ull)hi) << 32) | lo;
}

__device__ __forceinline__ uint block_reduce_u32(uint v, uint* red, uint* bc,
                                                 int lane, int wid, int tid) {
#pragma unroll
  for (int off = 32; off; off >>= 1) v += __shfl_down(v, off);
  if (lane == 0) red[wid] = v;
  __syncthreads();
  if (tid == 0) *bc = red[0] + red[1] + red[2] + red[3];
  __syncthreads();
  return *bc;
}

// (NT,4) -> 128-VGPR budget. R6 proved (NT,8)=64-cap spills the row (WRITE
// 131->287 MB). Block-per-row keeps ~3.5 rows/CU -> 1.8 MB dirty/XCD < 4 MB
// L2, so the zero-filled output lines survive until the scatter (R5/R8 lesson:
// wave-per-row = 15+ rows/CU overflows L2 and doubles write traffic).
__global__ __launch_bounds__(NT, 4) void kcomp_kernel(const float* __restrict__ x,
                                                      float* __restrict__ out) {
  const int tid  = threadIdx.x;
  const int lane = tid & 63;
  const int wid  = tid >> 6;
  const int row  = blockIdx.x;

  __shared__ ull   s_cand[4][2][CMAX];   // per-wave segments: 4 KB
  __shared__ uint  s_cnt[4][2];          // per-wave counters (wave-local: no init barrier)
  __shared__ float s_fsum[4][2];
  __shared__ uint  s_red[4];
  __shared__ uint  s_bc;

  if (lane == 0) { s_cnt[wid][0] = 0u; s_cnt[wid][1] = 0u; }  // same-wave DS: in-order

  const uint4* xr4 = reinterpret_cast<const uint4*>(x + (size_t)row * DIMS);

  // ---- pass 1 (fused): load 16 elems/thread, sums + speculative gather at PIV0 ----
  uint4 v0 = xr4[tid];
  uint4 v1 = xr4[256 + tid];
  uint4 v2 = xr4[512 + tid];
  uint4 v3 = xr4[768 + tid];

  float psum = 0.f, nmsum = 0.f;   // nmsum = sum of min(x,0)
#define PROC(RW, J, C) { \
    float f = __uint_as_float(RW); \
    psum += fmaxf(f, 0.f); nmsum += fminf(f, 0.f); \
    if ((int)(RW) >= (int)PIV0) { \
      ull K = (((ull)(RW)) << 32) | (ull)INV(J, C); \
      uint s = atomicAdd(&s_cnt[wid][0], 1u); if (s < CMAX) s_cand[wid][0][s] = K; } \
    if ((RW) >= PIVN) { \
      ull K = (((ull)((RW) ^ 0x80000000u)) << 32) | (ull)INV(J, C); \
      uint s = atomicAdd(&s_cnt[wid][1], 1u); if (s < CMAX) s_cand[wid][1][s] = K; } }
#define PROC4(V, J) PROC(V.x, J, 0) PROC(V.y, J, 1) PROC(V.z, J, 2) PROC(V.w, J, 3)
  PROC4(v0, 0) PROC4(v1, 1) PROC4(v2, 2) PROC4(v3, 3)
#undef PROC4
#undef PROC

  // ---- zero-fill the output row now; stores drain under reduce+sort, lines
  //      stay dirty in L2 until the scatter (few rows in flight per XCD) ----
  {
    float4 z; z.x = 0.f; z.y = 0.f; z.z = 0.f; z.w = 0.f;
    float4* o4 = reinterpret_cast<float4*>(out + (size_t)row * DIMS);
    o4[tid]       = z;
    o4[256 + tid] = z;
    o4[512 + tid] = z;
    o4[768 + tid] = z;
  }

  // wave-local sum reduce, then one barrier makes sums+counts block-visible
  {
    float p = psum, n = nmsum;
#pragma unroll
    for (int off = 1; off < 64; off <<= 1) {
      p += __shfl_xor(p, off, 64);
      n += __shfl_xor(n, off, 64);
    }
    if (lane == 0) { s_fsum[wid][0] = p; s_fsum[wid][1] = n; }
  }
  __syncthreads();  // B1

  const uint c0 = s_cnt[0][0] + s_cnt[1][0] + s_cnt[2][0] + s_cnt[3][0];
  const uint c1 = s_cnt[0][1] + s_cnt[1][1] + s_cnt[2][1] + s_cnt[3][1];
  const float psumT = s_fsum[0][0] + s_fsum[1][0] + s_fsum[2][0] + s_fsum[3][0];
  const float nsumT = -(s_fsum[0][1] + s_fsum[1][1] + s_fsum[2][1] + s_fsum[3][1]);

  // ---- cold path (~0.3% of rows, block-uniform): bisect over registers + regather ----
  const bool bad0 = (c0 < KSEL) | (c0 > CMAX);
  const bool bad1 = (c1 < KSEL) | (c1 > CMAX);
  if (bad0 | bad1) {
    for (int br = 0; br < 2; ++br) {
      const bool bad = br ? bad1 : bad0;
      if (!bad) continue;
      const uint ns = br ? c1 : c0;
      uint lo, hi, nlo;
      if (ns > CMAX) { lo = PIV0; hi = 0xFFFFFFFFu; nlo = ns; }
      else           { lo = 0u;   hi = PIV0;        nlo = (uint)DIMS; }
      bool st2 = false;
      for (int it = 0; it < 40; ++it) {
        if (hi - lo <= 1u) { st2 = (nlo > CMAX); break; }
        const uint mid = lo + ((hi - lo) >> 1);
        uint c = 0;
#define CNT(RW) { uint k = br ? BNk(RW) : BPk(RW); c += (k >= mid) ? 1u : 0u; }
#define CNT4(V) CNT(V.x) CNT(V.y) CNT(V.z) CNT(V.w)
        CNT4(v0) CNT4(v1) CNT4(v2) CNT4(v3)
#undef CNT4
#undef CNT
        const uint t = block_reduce_u32(c, s_red, &s_bc, lane, wid, tid);
        if (t >= KSEL) { lo = mid; nlo = t; if (t <= CMAX) break; }
        else hi = mid;
      }
      ull S;
      if (!st2) S = ((ull)lo) << 32;
      else {
        // >CMAX exact bit-ties at pivot: bisect the inverted-index word
        const uint pivot = lo;
        uint lo2 = 0u, hi2 = 0xFFFFFFFFu, nlo2 = nlo;
        for (int it = 0; it < 34 && nlo2 > CMAX; ++it) {
          const uint mid2 = lo2 + ((hi2 - lo2) >> 1);
          uint c = 0;
#define CNT2(RW, J, C) { uint k = br ? BNk(RW) : BPk(RW); \
          c += ((k > pivot) || (k == pivot && INV(J, C) >= mid2)) ? 1u : 0u; }
#define CNT24(V, J) CNT2(V.x, J, 0) CNT2(V.y, J, 1) CNT2(V.z, J, 2) CNT2(V.w, J, 3)
          CNT24(v0, 0) CNT24(v1, 1) CNT24(v2, 2) CNT24(v3, 3)
#undef CNT24
#undef CNT2
          const uint n = block_reduce_u32(c, s_red, &s_bc, lane, wid, tid);
          if (n >= KSEL) { lo2 = mid2; nlo2 = n; } else hi2 = mid2;
          if (hi2 - lo2 <= 1u) break;  // unique 64-bit keys => count <= CMAX
        }
        S = (((ull)pivot) << 32) | (ull)lo2;
      }
      // regather this branch into per-wave segments (own counter: in-order reset)
      if (lane == 0) s_cnt[wid][br] = 0u;
#define RGAT(RW, J, C) { uint k = br ? BNk(RW) : BPk(RW); \
      ull K = (((ull)k) << 32) | (ull)INV(J, C); \
      if (K >= S) { uint s = atomicAdd(&s_cnt[wid][br], 1u); if (s < CMAX) s_cand[wid][br][s] = K; } }
#define RGAT4(V, J) RGAT(V.x, J, 0) RGAT(V.y, J, 1) RGAT(V.z, J, 2) RGAT(V.w, J, 3)
      RGAT4(v0, 0) RGAT4(v1, 1) RGAT4(v2, 2) RGAT4(v3, 3)
#undef RGAT4
#undef RGAT
    }
    __syncthreads();  // B1b: regathered candidates visible to sort waves
  }

  // ---- sort: wave 0 = pos branch, wave 1 = neg branch; merge 4 segments, bitonic ----
  ull  vkey = 0ull;
  float ts  = 0.f;
  if (wid < 2) {
    const int br = wid;
    uint q0 = s_cnt[0][br]; if (q0 > CMAX) q0 = CMAX;
    uint q1 = s_cnt[1][br]; if (q1 > CMAX) q1 = CMAX;
    uint q2 = s_cnt[2][br]; if (q2 > CMAX) q2 = CMAX;
    uint q3 = s_cnt[3][br]; if (q3 > CMAX) q3 = CMAX;
    const uint o1 = q0, o2 = q0 + q1, o3 = o2 + q2;
    uint n = o3 + q3; if (n > CMAX) n = CMAX;

    ull v = 0ull;  // real keys are nonzero
    const uint l = (uint)lane;
    if (l < n) {
      if (l < o1)      v = s_cand[0][br][l];
      else if (l < o2) v = s_cand[1][br][l - o1];
      else if (l < o3) v = s_cand[2][br][l - o2];
      else             v = s_cand[3][br][l - o3];
    }

#pragma unroll
    for (int k = 2; k <= 64; k <<= 1) {
#pragma unroll
      for (int j = k >> 1; j > 0; j >>= 1) {
        const ull o = shflx64(v, j);
        const bool keepmin = (((lane & k) == 0) == ((lane & j) == 0));
        const ull mn = (v < o) ? v : o, mx = (v < o) ? o : v;
        v = keepmin ? mn : mx;
      }
    }
    // ascending: lanes 48..63 hold the top-16; 16-lane-group sum of their values
    ts = __uint_as_float((uint)(v >> 32));
#pragma unroll
    for (int off = 1; off < 16; off <<= 1) ts += __shfl_xor(ts, off, 64);
    vkey = v;
  }
  __syncthreads();  // B2: implies vmcnt drain -> all zero-fill stores ordered first

  // ---- scatter the 32 selected outputs into the still-dirty L2 lines ----
  if (wid < 2 && lane >= 48) {
    asm volatile("s_waitcnt vmcnt(0)" ::: "memory");  // belt-and-braces store order
    const float sum = wid ? nsumT : psumT;
    const float a   = ALPHA_C * (sum - ts);
    const float val = __uint_as_float((uint)(vkey >> 32));
    const uint  idx = ~((uint)vkey);
    float* orow = out + (size_t)row * DIMS;
    orow[idx] = wid ? -(val + a) : (val + a);
  }
}

extern "C" void kernel_launch(void* const* d_in, const int* in_sizes, int n_in,
                              void* d_out, int out_size, void* d_ws, size_t ws_size,
                              hipStream_t stream) {
  const float* x = (const float*)d_in[0];
  float* o = (float*)d_out;
  const int B = in_sizes[0] / DIMS;   // 8192 rows, one 256-thread block per row
  hipLaunchKernelGGL(kcomp_kernel, dim3(B), dim3(NT), 0, stream, x, o);
}

// Round 10
// 51.071 us; speedup vs baseline: 2.5989x; 1.0218x over previous
//
#include <hip/hip_runtime.h>
#include <stdint.h>

typedef unsigned uint;
typedef unsigned long long ull;

#define DIMS   4096
#define NT     256
#define KSEL   16            // top-k per branch (KTOP/2)
#define CMAX   64            // candidate capacity per branch
#define ALPHA_C 6.26f
#define PIV0   0x40133333u   // bits(2.3f): ~44 expected survivors per branch
#define PIVN   0xC0133333u   // raw >= PIVN (unsigned)  <=>  neg-key >= PIV0

#define BPk(raw) (((int)(raw) > 0) ? (raw) : 0u)                  // key of relu(x)
#define BNk(raw) (((int)(raw) < 0) ? ((raw) ^ 0x80000000u) : 0u)  // key of max(-x,0)
// element index of chunk J, comp C in this thread: idx = J*1024 + tid*4 + C
// inverted so smaller index -> larger low word (jax tie-break: lowest index first)
#define INV(J,C) (~((((uint)(J)) << 10) + (((uint)tid) << 2) + ((uint)(C))))

typedef float f4 __attribute__((ext_vector_type(4)));

__device__ __forceinline__ ull shflx64(ull v, int m) {
  uint lo = (uint)v, hi = (uint)(v >> 32);
  lo = __shfl_xor(lo, m, 64);
  hi = __shfl_xor(hi, m, 64);
  return (((ull)hi) << 32) | lo;
}

__device__ __forceinline__ uint block_reduce_u32(uint v, uint* red, uint* bc,
                                                 int lane, int wid, int tid) {
#pragma unroll
  for (int off = 32; off; off >>= 1) v += __shfl_down(v, off);
  if (lane == 0) red[wid] = v;
  __syncthreads();
  if (tid == 0) *bc = red[0] + red[1] + red[2] + red[3];
  __syncthreads();
  return *bc;
}

// (NT,4) -> 128-VGPR budget (R6: (NT,8)=64-cap spilled the row).
// Block-per-row: ~3.5 rows/CU keeps zero-filled out-lines dirty in L2 until
// the scatter (R5/R8: wave-per-row overflowed L2, doubling write traffic).
// R10 change: output stores are NON-TEMPORAL (evict-first) so the out stream
// (131 MB, zero cross-replay locality) stops thrashing x (128 MB, perfect
// cross-replay locality) out of the 256 MB memory-side L3. Expect FETCH 65->
// <25 MB steady-state.
__global__ __launch_bounds__(NT, 4) void kcomp_kernel(const float* __restrict__ x,
                                                      float* __restrict__ out) {
  const int tid  = threadIdx.x;
  const int lane = tid & 63;
  const int wid  = tid >> 6;
  const int row  = blockIdx.x;

  __shared__ ull   s_cand[4][2][CMAX];   // per-wave segments: 4 KB
  __shared__ uint  s_cnt[4][2];          // per-wave counters (wave-local: no init barrier)
  __shared__ float s_fsum[4][2];
  __shared__ uint  s_red[4];
  __shared__ uint  s_bc;

  if (lane == 0) { s_cnt[wid][0] = 0u; s_cnt[wid][1] = 0u; }  // same-wave DS: in-order

  const uint4* xr4 = reinterpret_cast<const uint4*>(x + (size_t)row * DIMS);

  // ---- pass 1 (fused): load 16 elems/thread, sums + speculative gather at PIV0 ----
  uint4 v0 = xr4[tid];
  uint4 v1 = xr4[256 + tid];
  uint4 v2 = xr4[512 + tid];
  uint4 v3 = xr4[768 + tid];

  float psum = 0.f, nmsum = 0.f;   // nmsum = sum of min(x,0)
#define PROC(RW, J, C) { \
    float f = __uint_as_float(RW); \
    psum += fmaxf(f, 0.f); nmsum += fminf(f, 0.f); \
    if ((int)(RW) >= (int)PIV0) { \
      ull K = (((ull)(RW)) << 32) | (ull)INV(J, C); \
      uint s = atomicAdd(&s_cnt[wid][0], 1u); if (s < CMAX) s_cand[wid][0][s] = K; } \
    if ((RW) >= PIVN) { \
      ull K = (((ull)((RW) ^ 0x80000000u)) << 32) | (ull)INV(J, C); \
      uint s = atomicAdd(&s_cnt[wid][1], 1u); if (s < CMAX) s_cand[wid][1][s] = K; } }
#define PROC4(V, J) PROC(V.x, J, 0) PROC(V.y, J, 1) PROC(V.z, J, 2) PROC(V.w, J, 3)
  PROC4(v0, 0) PROC4(v1, 1) PROC4(v2, 2) PROC4(v3, 3)
#undef PROC4
#undef PROC

  // ---- zero-fill the output row (non-temporal); stores drain under reduce+sort,
  //      lines stay dirty in L2 until the scatter, and skip L3 allocation ----
  {
    f4 z = {0.f, 0.f, 0.f, 0.f};
    f4* o4 = reinterpret_cast<f4*>(out + (size_t)row * DIMS);
    __builtin_nontemporal_store(z, &o4[tid]);
    __builtin_nontemporal_store(z, &o4[256 + tid]);
    __builtin_nontemporal_store(z, &o4[512 + tid]);
    __builtin_nontemporal_store(z, &o4[768 + tid]);
  }

  // wave-local sum reduce, then one barrier makes sums+counts block-visible
  {
    float p = psum, n = nmsum;
#pragma unroll
    for (int off = 1; off < 64; off <<= 1) {
      p += __shfl_xor(p, off, 64);
      n += __shfl_xor(n, off, 64);
    }
    if (lane == 0) { s_fsum[wid][0] = p; s_fsum[wid][1] = n; }
  }
  __syncthreads();  // B1

  const uint c0 = s_cnt[0][0] + s_cnt[1][0] + s_cnt[2][0] + s_cnt[3][0];
  const uint c1 = s_cnt[0][1] + s_cnt[1][1] + s_cnt[2][1] + s_cnt[3][1];
  const float psumT = s_fsum[0][0] + s_fsum[1][0] + s_fsum[2][0] + s_fsum[3][0];
  const float nsumT = -(s_fsum[0][1] + s_fsum[1][1] + s_fsum[2][1] + s_fsum[3][1]);

  // ---- cold path (~0.3% of rows, block-uniform): bisect over registers + regather ----
  const bool bad0 = (c0 < KSEL) | (c0 > CMAX);
  const bool bad1 = (c1 < KSEL) | (c1 > CMAX);
  if (bad0 | bad1) {
    for (int br = 0; br < 2; ++br) {
      const bool bad = br ? bad1 : bad0;
      if (!bad) continue;
      const uint ns = br ? c1 : c0;
      uint lo, hi, nlo;
      if (ns > CMAX) { lo = PIV0; hi = 0xFFFFFFFFu; nlo = ns; }
      else           { lo = 0u;   hi = PIV0;        nlo = (uint)DIMS; }
      bool st2 = false;
      for (int it = 0; it < 40; ++it) {
        if (hi - lo <= 1u) { st2 = (nlo > CMAX); break; }
        const uint mid = lo + ((hi - lo) >> 1);
        uint c = 0;
#define CNT(RW) { uint k = br ? BNk(RW) : BPk(RW); c += (k >= mid) ? 1u : 0u; }
#define CNT4(V) CNT(V.x) CNT(V.y) CNT(V.z) CNT(V.w)
        CNT4(v0) CNT4(v1) CNT4(v2) CNT4(v3)
#undef CNT4
#undef CNT
        const uint t = block_reduce_u32(c, s_red, &s_bc, lane, wid, tid);
        if (t >= KSEL) { lo = mid; nlo = t; if (t <= CMAX) break; }
        else hi = mid;
      }
      ull S;
      if (!st2) S = ((ull)lo) << 32;
      else {
        // >CMAX exact bit-ties at pivot: bisect the inverted-index word
        const uint pivot = lo;
        uint lo2 = 0u, hi2 = 0xFFFFFFFFu, nlo2 = nlo;
        for (int it = 0; it < 34 && nlo2 > CMAX; ++it) {
          const uint mid2 = lo2 + ((hi2 - lo2) >> 1);
          uint c = 0;
#define CNT2(RW, J, C) { uint k = br ? BNk(RW) : BPk(RW); \
          c += ((k > pivot) || (k == pivot && INV(J, C) >= mid2)) ? 1u : 0u; }
#define CNT24(V, J) CNT2(V.x, J, 0) CNT2(V.y, J, 1) CNT2(V.z, J, 2) CNT2(V.w, J, 3)
          CNT24(v0, 0) CNT24(v1, 1) CNT24(v2, 2) CNT24(v3, 3)
#undef CNT24
#undef CNT2
          const uint n = block_reduce_u32(c, s_red, &s_bc, lane, wid, tid);
          if (n >= KSEL) { lo2 = mid2; nlo2 = n; } else hi2 = mid2;
          if (hi2 - lo2 <= 1u) break;  // unique 64-bit keys => count <= CMAX
        }
        S = (((ull)pivot) << 32) | (ull)lo2;
      }
      // regather this branch into per-wave segments (own counter: in-order reset)
      if (lane == 0) s_cnt[wid][br] = 0u;
#define RGAT(RW, J, C) { uint k = br ? BNk(RW) : BPk(RW); \
      ull K = (((ull)k) << 32) | (ull)INV(J, C); \
      if (K >= S) { uint s = atomicAdd(&s_cnt[wid][br], 1u); if (s < CMAX) s_cand[wid][br][s] = K; } }
#define RGAT4(V, J) RGAT(V.x, J, 0) RGAT(V.y, J, 1) RGAT(V.z, J, 2) RGAT(V.w, J, 3)
      RGAT4(v0, 0) RGAT4(v1, 1) RGAT4(v2, 2) RGAT4(v3, 3)
#undef RGAT4
#undef RGAT
    }
    __syncthreads();  // B1b: regathered candidates visible to sort waves
  }

  // ---- sort: wave 0 = pos branch, wave 1 = neg branch; merge 4 segments, bitonic ----
  ull  vkey = 0ull;
  float ts  = 0.f;
  if (wid < 2) {
    const int br = wid;
    uint q0 = s_cnt[0][br]; if (q0 > CMAX) q0 = CMAX;
    uint q1 = s_cnt[1][br]; if (q1 > CMAX) q1 = CMAX;
    uint q2 = s_cnt[2][br]; if (q2 > CMAX) q2 = CMAX;
    uint q3 = s_cnt[3][br]; if (q3 > CMAX) q3 = CMAX;
    const uint o1 = q0, o2 = q0 + q1, o3 = o2 + q2;
    uint n = o3 + q3; if (n > CMAX) n = CMAX;

    ull v = 0ull;  // real keys are nonzero
    const uint l = (uint)lane;
    if (l < n) {
      if (l < o1)      v = s_cand[0][br][l];
      else if (l < o2) v = s_cand[1][br][l - o1];
      else if (l < o3) v = s_cand[2][br][l - o2];
      else             v = s_cand[3][br][l - o3];
    }

#pragma unroll
    for (int k = 2; k <= 64; k <<= 1) {
#pragma unroll
      for (int j = k >> 1; j > 0; j >>= 1) {
        const ull o = shflx64(v, j);
        const bool keepmin = (((lane & k) == 0) == ((lane & j) == 0));
        const ull mn = (v < o) ? v : o, mx = (v < o) ? o : v;
        v = keepmin ? mn : mx;
      }
    }
    // ascending: lanes 48..63 hold the top-16; 16-lane-group sum of their values
    ts = __uint_as_float((uint)(v >> 32));
#pragma unroll
    for (int off = 1; off < 16; off <<= 1) ts += __shfl_xor(ts, off, 64);
    vkey = v;
  }
  __syncthreads();  // B2: implies vmcnt drain -> all zero-fill stores ordered first

  // ---- scatter the 32 selected outputs into the still-dirty L2 lines ----
  if (wid < 2 && lane >= 48) {
    asm volatile("s_waitcnt vmcnt(0)" ::: "memory");  // belt-and-braces store order
    const float sum = wid ? nsumT : psumT;
    const float a   = ALPHA_C * (sum - ts);
    const float val = __uint_as_float((uint)(vkey >> 32));
    const uint  idx = ~((uint)vkey);
    float* orow = out + (size_t)row * DIMS;
    __builtin_nontemporal_store(wid ? -(val + a) : (val + a), &orow[idx]);
  }
}

extern "C" void kernel_launch(void* const* d_in, const int* in_sizes, int n_in,
                              void* d_out, int out_size, void* d_ws, size_t ws_size,
                              hipStream_t stream) {
  const float* x = (const float*)d_in[0];
  float* o = (float*)d_out;
  const int B = in_sizes[0] / DIMS;   // 8192 rows, one 256-thread block per row
  hipLaunchKernelGGL(kcomp_kernel, dim3(B), dim3(NT), 0, stream, x, o);
}

// Round 11
// 47.431 us; speedup vs baseline: 2.7984x; 1.0767x over previous
//
#include <hip/hip_runtime.h>
#include <stdint.h>

typedef unsigned uint;
typedef unsigned long long ull;

#define DIMS   4096
#define NT     256
#define KSEL   16            // top-k per branch (KTOP/2)
#define CMAX   64            // candidate capacity per branch
#define ALPHA_C 6.26f
#define PIV0   0x40133333u   // bits(2.3f): ~44 expected survivors per branch
#define PIVN   0xC0133333u   // raw >= PIVN (unsigned)  <=>  neg-key >= PIV0

#define BPk(raw) (((int)(raw) > 0) ? (raw) : 0u)                  // key of relu(x)
#define BNk(raw) (((int)(raw) < 0) ? ((raw) ^ 0x80000000u) : 0u)  // key of max(-x,0)
// element index of chunk J, comp C in this thread: idx = J*1024 + tid*4 + C
// inverted so smaller index -> larger low word (jax tie-break: lowest index first)
#define INV(J,C) (~((((uint)(J)) << 10) + (((uint)tid) << 2) + ((uint)(C))))

typedef float f4 __attribute__((ext_vector_type(4)));

__device__ __forceinline__ ull shflx64(ull v, int m) {
  uint lo = (uint)v, hi = (uint)(v >> 32);
  lo = __shfl_xor(lo, m, 64);
  hi = __shfl_xor(hi, m, 64);
  return (((ull)hi) << 32) | lo;
}

__device__ __forceinline__ uint block_reduce_u32(uint v, uint* red, uint* bc,
                                                 int lane, int wid, int tid) {
#pragma unroll
  for (int off = 32; off; off >>= 1) v += __shfl_down(v, off);
  if (lane == 0) red[wid] = v;
  __syncthreads();
  if (tid == 0) *bc = red[0] + red[1] + red[2] + red[3];
  __syncthreads();
  return *bc;
}

// (NT,6) -> 85-VGPR cap; kernel compiles to ~44 VGPR, so no spill (unlike R6,
// where the reg-resident-row variant NEEDED ~90 and (NT,8)'s 64-cap spilled).
// 6 blocks/CU = 24 waves = 75% occupancy cap, up from (NT,4)'s 45%: more loads
// in flight -> higher achieved HBM BW (R10 was 4.05 of 6.3 TB/s achievable).
// Dirty-output footprint: 6 rows x 16 KB x 32 CU = 3 MB/XCD < 4 MB L2, so the
// zero-fill -> scatter write-merge still holds (R5/R8 lesson).
__global__ __launch_bounds__(NT, 6) void kcomp_kernel(const float* __restrict__ x,
                                                      float* __restrict__ out) {
  const int tid  = threadIdx.x;
  const int lane = tid & 63;
  const int wid  = tid >> 6;
  const int row  = blockIdx.x;

  __shared__ ull   s_cand[4][2][CMAX];   // per-wave segments: 4 KB
  __shared__ uint  s_cnt[4][2];          // per-wave counters (wave-local: no init barrier)
  __shared__ float s_fsum[4][2];
  __shared__ uint  s_red[4];
  __shared__ uint  s_bc;

  if (lane == 0) { s_cnt[wid][0] = 0u; s_cnt[wid][1] = 0u; }  // same-wave DS: in-order

  const uint4* xr4 = reinterpret_cast<const uint4*>(x + (size_t)row * DIMS);

  // ---- pass 1 (fused): load 16 elems/thread, sums + speculative gather at PIV0 ----
  uint4 v0 = xr4[tid];
  uint4 v1 = xr4[256 + tid];
  uint4 v2 = xr4[512 + tid];
  uint4 v3 = xr4[768 + tid];

  float psum = 0.f, nmsum = 0.f;   // nmsum = sum of min(x,0)
#define PROC(RW, J, C) { \
    float f = __uint_as_float(RW); \
    psum += fmaxf(f, 0.f); nmsum += fminf(f, 0.f); \
    if ((int)(RW) >= (int)PIV0) { \
      ull K = (((ull)(RW)) << 32) | (ull)INV(J, C); \
      uint s = atomicAdd(&s_cnt[wid][0], 1u); if (s < CMAX) s_cand[wid][0][s] = K; } \
    if ((RW) >= PIVN) { \
      ull K = (((ull)((RW) ^ 0x80000000u)) << 32) | (ull)INV(J, C); \
      uint s = atomicAdd(&s_cnt[wid][1], 1u); if (s < CMAX) s_cand[wid][1][s] = K; } }
#define PROC4(V, J) PROC(V.x, J, 0) PROC(V.y, J, 1) PROC(V.z, J, 2) PROC(V.w, J, 3)
  PROC4(v0, 0) PROC4(v1, 1) PROC4(v2, 2) PROC4(v3, 3)
#undef PROC4
#undef PROC

  // ---- zero-fill the output row; stores drain under reduce+sort, lines stay
  //      dirty in L2 until the scatter (few rows in flight per XCD) ----
  {
    f4 z = {0.f, 0.f, 0.f, 0.f};
    f4* o4 = reinterpret_cast<f4*>(out + (size_t)row * DIMS);
    __builtin_nontemporal_store(z, &o4[tid]);
    __builtin_nontemporal_store(z, &o4[256 + tid]);
    __builtin_nontemporal_store(z, &o4[512 + tid]);
    __builtin_nontemporal_store(z, &o4[768 + tid]);
  }

  // wave-local sum reduce, then one barrier makes sums+counts block-visible
  {
    float p = psum, n = nmsum;
#pragma unroll
    for (int off = 1; off < 64; off <<= 1) {
      p += __shfl_xor(p, off, 64);
      n += __shfl_xor(n, off, 64);
    }
    if (lane == 0) { s_fsum[wid][0] = p; s_fsum[wid][1] = n; }
  }
  __syncthreads();  // B1

  const uint c0 = s_cnt[0][0] + s_cnt[1][0] + s_cnt[2][0] + s_cnt[3][0];
  const uint c1 = s_cnt[0][1] + s_cnt[1][1] + s_cnt[2][1] + s_cnt[3][1];
  const float psumT = s_fsum[0][0] + s_fsum[1][0] + s_fsum[2][0] + s_fsum[3][0];
  const float nsumT = -(s_fsum[0][1] + s_fsum[1][1] + s_fsum[2][1] + s_fsum[3][1]);

  // ---- cold path (~0.3% of rows, block-uniform): bisect over registers + regather ----
  const bool bad0 = (c0 < KSEL) | (c0 > CMAX);
  const bool bad1 = (c1 < KSEL) | (c1 > CMAX);
  if (bad0 | bad1) {
    for (int br = 0; br < 2; ++br) {
      const bool bad = br ? bad1 : bad0;
      if (!bad) continue;
      const uint ns = br ? c1 : c0;
      uint lo, hi, nlo;
      if (ns > CMAX) { lo = PIV0; hi = 0xFFFFFFFFu; nlo = ns; }
      else           { lo = 0u;   hi = PIV0;        nlo = (uint)DIMS; }
      bool st2 = false;
      for (int it = 0; it < 40; ++it) {
        if (hi - lo <= 1u) { st2 = (nlo > CMAX); break; }
        const uint mid = lo + ((hi - lo) >> 1);
        uint c = 0;
#define CNT(RW) { uint k = br ? BNk(RW) : BPk(RW); c += (k >= mid) ? 1u : 0u; }
#define CNT4(V) CNT(V.x) CNT(V.y) CNT(V.z) CNT(V.w)
        CNT4(v0) CNT4(v1) CNT4(v2) CNT4(v3)
#undef CNT4
#undef CNT
        const uint t = block_reduce_u32(c, s_red, &s_bc, lane, wid, tid);
        if (t >= KSEL) { lo = mid; nlo = t; if (t <= CMAX) break; }
        else hi = mid;
      }
      ull S;
      if (!st2) S = ((ull)lo) << 32;
      else {
        // >CMAX exact bit-ties at pivot: bisect the inverted-index word
        const uint pivot = lo;
        uint lo2 = 0u, hi2 = 0xFFFFFFFFu, nlo2 = nlo;
        for (int it = 0; it < 34 && nlo2 > CMAX; ++it) {
          const uint mid2 = lo2 + ((hi2 - lo2) >> 1);
          uint c = 0;
#define CNT2(RW, J, C) { uint k = br ? BNk(RW) : BPk(RW); \
          c += ((k > pivot) || (k == pivot && INV(J, C) >= mid2)) ? 1u : 0u; }
#define CNT24(V, J) CNT2(V.x, J, 0) CNT2(V.y, J, 1) CNT2(V.z, J, 2) CNT2(V.w, J, 3)
          CNT24(v0, 0) CNT24(v1, 1) CNT24(v2, 2) CNT24(v3, 3)
#undef CNT24
#undef CNT2
          const uint n = block_reduce_u32(c, s_red, &s_bc, lane, wid, tid);
          if (n >= KSEL) { lo2 = mid2; nlo2 = n; } else hi2 = mid2;
          if (hi2 - lo2 <= 1u) break;  // unique 64-bit keys => count <= CMAX
        }
        S = (((ull)pivot) << 32) | (ull)lo2;
      }
      // regather this branch into per-wave segments (own counter: in-order reset)
      if (lane == 0) s_cnt[wid][br] = 0u;
#define RGAT(RW, J, C) { uint k = br ? BNk(RW) : BPk(RW); \
      ull K = (((ull)k) << 32) | (ull)INV(J, C); \
      if (K >= S) { uint s = atomicAdd(&s_cnt[wid][br], 1u); if (s < CMAX) s_cand[wid][br][s] = K; } }
#define RGAT4(V, J) RGAT(V.x, J, 0) RGAT(V.y, J, 1) RGAT(V.z, J, 2) RGAT(V.w, J, 3)
      RGAT4(v0, 0) RGAT4(v1, 1) RGAT4(v2, 2) RGAT4(v3, 3)
#undef RGAT4
#undef RGAT
    }
    __syncthreads();  // B1b: regathered candidates visible to sort waves
  }

  // ---- sort: wave 0 = pos branch, wave 1 = neg branch; merge 4 segments, bitonic ----
  ull  vkey = 0ull;
  float ts  = 0.f;
  if (wid < 2) {
    const int br = wid;
    uint q0 = s_cnt[0][br]; if (q0 > CMAX) q0 = CMAX;
    uint q1 = s_cnt[1][br]; if (q1 > CMAX) q1 = CMAX;
    uint q2 = s_cnt[2][br]; if (q2 > CMAX) q2 = CMAX;
    uint q3 = s_cnt[3][br]; if (q3 > CMAX) q3 = CMAX;
    const uint o1 = q0, o2 = q0 + q1, o3 = o2 + q2;
    uint n = o3 + q3; if (n > CMAX) n = CMAX;

    ull v = 0ull;  // real keys are nonzero
    const uint l = (uint)lane;
    if (l < n) {
      if (l < o1)      v = s_cand[0][br][l];
      else if (l < o2) v = s_cand[1][br][l - o1];
      else if (l < o3) v = s_cand[2][br][l - o2];
      else             v = s_cand[3][br][l - o3];
    }

#pragma unroll
    for (int k = 2; k <= 64; k <<= 1) {
#pragma unroll
      for (int j = k >> 1; j > 0; j >>= 1) {
        const ull o = shflx64(v, j);
        const bool keepmin = (((lane & k) == 0) == ((lane & j) == 0));
        const ull mn = (v < o) ? v : o, mx = (v < o) ? o : v;
        v = keepmin ? mn : mx;
      }
    }
    // ascending: lanes 48..63 hold the top-16; 16-lane-group sum of their values
    ts = __uint_as_float((uint)(v >> 32));
#pragma unroll
    for (int off = 1; off < 16; off <<= 1) ts += __shfl_xor(ts, off, 64);
    vkey = v;
  }
  __syncthreads();  // B2: implies vmcnt drain -> all zero-fill stores ordered first

  // ---- scatter the 32 selected outputs into the still-dirty L2 lines ----
  if (wid < 2 && lane >= 48) {
    asm volatile("s_waitcnt vmcnt(0)" ::: "memory");  // belt-and-braces store order
    const float sum = wid ? nsumT : psumT;
    const float a   = ALPHA_C * (sum - ts);
    const float val = __uint_as_float((uint)(vkey >> 32));
    const uint  idx = ~((uint)vkey);
    float* orow = out + (size_t)row * DIMS;
    __builtin_nontemporal_store(wid ? -(val + a) : (val + a), &orow[idx]);
  }
}

extern "C" void kernel_launch(void* const* d_in, const int* in_sizes, int n_in,
                              void* d_out, int out_size, void* d_ws, size_t ws_size,
                              hipStream_t stream) {
  const float* x = (const float*)d_in[0];
  float* o = (float*)d_out;
  const int B = in_sizes[0] / DIMS;   // 8192 rows, one 256-thread block per row
  hipLaunchKernelGGL(kcomp_kernel, dim3(B), dim3(NT), 0, stream, x, o);
}